// Round 9
// baseline (127.795 us; speedup 1.0000x reference)
//
#include <hip/hip_runtime.h>
#include <math.h>

// LearnableVisitEncoder — R9.
// R8 post-mortem: pool near its gather floor; vocab is the largest
// controllable term and runs 5-10x above its issue floor. Diagnosis: in the
// R5 shape each layer's 16 B-frag L2 loads sit BETWEEN barriers -> 3 exposed
// L2-latency bubbles per block. R9 = R6 geometry + R7 register-frags:
// 1250 blocks x 8 waves (10000 waves), 1 n-tile/wave, 24 B-frag short8s
// (all 3 layers, 96 VGPR) hoisted to registers in the prologue, overlapped
// with the emb HBM stage. Layer loop has zero global loads.
// pool_rho kept from R8 verbatim (single-variable round).

#define DIM 128
#define MT 16
#define XLDP 136  // bf16 LDS row stride (272B = 17*16B): 16B-aligned rows

typedef float f32x4 __attribute__((ext_vector_type(4)));
typedef short short8 __attribute__((ext_vector_type(8)));
typedef unsigned short u16x8 __attribute__((ext_vector_type(8)));

#define MFMA(a, b, c) __builtin_amdgcn_mfma_f32_16x16x32_bf16(a, b, c, 0, 0, 0)

__device__ __forceinline__ float fast_rcp(float x) {
  return __builtin_amdgcn_rcpf(x);
}
__device__ __forceinline__ float silu_f(float v) {
  return v * fast_rcp(1.0f + __expf(-v));
}
__device__ __forceinline__ float tanh_f(float v) {
  float t = __expf(2.0f * v);       // inf-safe: v>>0 -> 1, v<<0 -> -1
  return 1.0f - 2.0f * fast_rcp(t + 1.0f);
}

// round-to-nearest bf16 split: x ~= hi + lo, |x-hi-lo| <= 2^-18 |x|
__device__ __forceinline__ unsigned short bf16_hi(float x, float* hif) {
  unsigned u = __builtin_bit_cast(unsigned, x);
  unsigned h = (u + 0x8000u) >> 16;
  *hif = __builtin_bit_cast(float, h << 16);
  return (unsigned short)h;
}
__device__ __forceinline__ unsigned short bf16_rd(float x) {
  unsigned u = __builtin_bit_cast(unsigned, x);
  return (unsigned short)((u + 0x8000u) >> 16);
}
// fp16 pack/unpack (v_cvt_f16_f32 / v_cvt_f32_f16)
__device__ __forceinline__ unsigned short f2h(float x) {
  return __builtin_bit_cast(unsigned short, (_Float16)x);
}
__device__ __forceinline__ float h2f(unsigned short u) {
  return (float)__builtin_bit_cast(_Float16, u);
}

// ---------------- W fragment prep ----------------
// frag element (t,s,lane,j) = W[k][n], k = s*32 + (lane>>4)*8 + j,
// n = t*16 + (lane&15); stored flat at ((t*4+s)*64+lane)*8+j.
__global__ __launch_bounds__(256) void prep_wfrags(
    const float* __restrict__ W1, const float* __restrict__ W2,
    const float* __restrict__ Wa1, const float* __restrict__ Wr1,
    const float* __restrict__ Wr2, unsigned short* __restrict__ frags) {
  const int m = blockIdx.x >> 3, chunk = blockIdx.x & 7;
  const float* W = (m == 0) ? W1 : (m == 1) ? W2 : (m == 2) ? Wa1
                  : (m == 3) ? Wr1 : Wr2;
  unsigned short* fh = frags + (size_t)m * 32768;
  unsigned short* fl = fh + 16384;
  const int fid = chunk * 256 + threadIdx.x;  // (t,s,lane) flat, < 2048
  const int lane = fid & 63, s = (fid >> 6) & 3, t = fid >> 8;
  const int k0 = s * 32 + (lane >> 4) * 8;
  const int n = t * 16 + (lane & 15);
#pragma unroll
  for (int j = 0; j < 8; ++j) {
    float w = W[(size_t)(k0 + j) * DIM + n];
    float hf;
    unsigned short h = bf16_hi(w, &hf);
    fh[fid * 8 + j] = h;
    fl[fid * 8 + j] = bf16_rd(w - hf);
  }
}

// convert one float4 (this thread's 16B of a 16x128 tile) into hi/lo LDS
__device__ __forceinline__ void stage_from_reg(float4 v,
                                               unsigned short (*xh)[XLDP],
                                               unsigned short (*xl)[XLDP],
                                               int tid) {
  int r = tid >> 5, c4 = tid & 31;  // 512 float4 = 16 rows x 32
  float hf;
  ushort4 h, l;
  h.x = bf16_hi(v.x, &hf); l.x = bf16_rd(v.x - hf);
  h.y = bf16_hi(v.y, &hf); l.y = bf16_rd(v.y - hf);
  h.z = bf16_hi(v.z, &hf); l.z = bf16_rd(v.z - hf);
  h.w = bf16_hi(v.w, &hf); l.w = bf16_rd(v.w - hf);
  *(ushort4*)&xh[r][c4 * 4] = h;
  *(ushort4*)&xl[r][c4 * 4] = l;
}

// GEMM with register-resident B-frags: 2 accumulators (chain depth 8),
// 3 bf16 cross-products (hh, hl, lh): fp32-level accuracy.
__device__ __forceinline__ f32x4 gemm_reg(const unsigned short (*xh)[XLDP],
                                          const unsigned short (*xl)[XLDP],
                                          const short8 bh[4],
                                          const short8 bl[4], int lane) {
  const int cr = lane & 15, g = lane >> 4;
  f32x4 a0 = {0.f, 0.f, 0.f, 0.f}, a1 = {0.f, 0.f, 0.f, 0.f};
#pragma unroll
  for (int s = 0; s < 4; ++s) {
    short8 ah = *(const short8*)&xh[cr][s * 32 + g * 8];
    short8 al = *(const short8*)&xl[cr][s * 32 + g * 8];
    a0 = MFMA(ah, bh[s], a0);
    a1 = MFMA(ah, bl[s], a1);
    a1 = MFMA(al, bh[s], a1);
  }
  return a0 + a1;
}

// one 16x128 @ 128x(16*NT) slice from L2 frag arrays (pool_rho path)
template <int NT>
__device__ __forceinline__ void gemm_frag(const unsigned short (*xh)[XLDP],
                                          const unsigned short (*xl)[XLDP],
                                          const unsigned short* __restrict__ bhp,
                                          const unsigned short* __restrict__ blp,
                                          int tt0, int lane, f32x4 acc[NT]) {
  const int cr = lane & 15, g = lane >> 4;
  short8 ah[4], al[4];
#pragma unroll
  for (int s = 0; s < 4; ++s) {  // A-frag: m=lane&15, k=s*32+(lane>>4)*8+j
    ah[s] = *(const short8*)&xh[cr][s * 32 + g * 8];
    al[s] = *(const short8*)&xl[cr][s * 32 + g * 8];
  }
#pragma unroll
  for (int t = 0; t < NT; ++t) {
    short8 bh[4], bl[4];
#pragma unroll
    for (int s = 0; s < 4; ++s) {
      bh[s] = *(const short8*)(bhp +
          ((size_t)((tt0 + t) * 4 + s) * 64 + lane) * 8);
      bl[s] = *(const short8*)(blp +
          ((size_t)((tt0 + t) * 4 + s) * 64 + lane) * 8);
    }
    f32x4 a0 = {0.f, 0.f, 0.f, 0.f}, a1 = {0.f, 0.f, 0.f, 0.f};
#pragma unroll
    for (int s = 0; s < 4; ++s) {
      a0 = MFMA(ah[s], bh[s], a0);
      a1 = MFMA(ah[s], bl[s], a1);
      a1 = MFMA(al[s], bh[s], a1);
    }
    acc[t] = a0 + a1;
  }
}

// ---------------- Kernel A: vocab side ----------------
// 512 threads = 8 waves, grid 1250 (10000 waves). Wave wid owns n-tile wid;
// its 24 B-frag short8s (3 layers x 4 k-slices x hi/lo) live in registers,
// loaded in the prologue overlapped with the emb stage.
__global__ __launch_bounds__(512, 2) void vocab_mfma(
    const float* __restrict__ emb, const unsigned short* __restrict__ frags,
    const float* __restrict__ b1, const float* __restrict__ b2,
    const float* __restrict__ ba1, const float* __restrict__ wa2,
    const float* __restrict__ ba2, unsigned short* __restrict__ H2h,
    float* __restrict__ L) {
  __shared__ unsigned short Xh[2][MT][XLDP], Xl[2][MT][XLDP];
  __shared__ float sP[8][MT];
  const int tid = threadIdx.x, wid = tid >> 6, lane = tid & 63;
  const int cr = lane & 15, g = lane >> 4;
  const int m0 = blockIdx.x * MT;

  // issue emb load first (HBM, longest latency)
  float4 av = ((const float4*)(emb + (size_t)m0 * DIM))[tid];

  // B-frags for all 3 layers into registers (96 VGPR)
  short8 B1h[4], B1l[4], B2h[4], B2l[4], B3h[4], B3l[4];
#pragma unroll
  for (int s = 0; s < 4; ++s) {
    const size_t off = ((size_t)(wid * 4 + s) * 64 + lane) * 8;
    B1h[s] = *(const short8*)(frags + off);
    B1l[s] = *(const short8*)(frags + 16384 + off);
    B2h[s] = *(const short8*)(frags + 32768 + off);
    B2l[s] = *(const short8*)(frags + 32768 + 16384 + off);
    B3h[s] = *(const short8*)(frags + 65536 + off);
    B3l[s] = *(const short8*)(frags + 65536 + 16384 + off);
  }

  const int col = wid * 16 + cr;
  const float bv1 = b1[col], bv2 = b2[col];
  const float bav = ba1[col], wav = wa2[col];

  stage_from_reg(av, Xh[0], Xl[0], tid);
  __syncthreads();

  // layer 1: silu(emb@W1+b1) -> Xh/Xl[1]
  {
    f32x4 acc = gemm_reg(Xh[0], Xl[0], B1h, B1l, lane);
#pragma unroll
    for (int r = 0; r < 4; ++r) {
      float o = silu_f(acc[r] + bv1);
      float hf;
      Xh[1][g * 4 + r][col] = bf16_hi(o, &hf);
      Xl[1][g * 4 + r][col] = bf16_rd(o - hf);
    }
  }
  __syncthreads();
  // layer 2: silu(.@W2+b2) -> Xh/Xl[0] + global H2h (fp16)
  {
    f32x4 acc = gemm_reg(Xh[1], Xl[1], B2h, B2l, lane);
#pragma unroll
    for (int r = 0; r < 4; ++r) {
      float o = silu_f(acc[r] + bv2);
      float hf;
      const int row = g * 4 + r;
      Xh[0][row][col] = bf16_hi(o, &hf);
      Xl[0][row][col] = bf16_rd(o - hf);
      H2h[(size_t)(m0 + row) * DIM + col] = f2h(o);
    }
  }
  __syncthreads();
  // layer 3: tanh(.@Wa1+ba1) . wa2 -> sP -> L
  {
    f32x4 acc = gemm_reg(Xh[0], Xl[0], B3h, B3l, lane);
#pragma unroll
    for (int r = 0; r < 4; ++r) {
      float p = tanh_f(acc[r] + bav) * wav;
      p += __shfl_xor(p, 1, 64);  // reduce over the 16 cols (lane&15)
      p += __shfl_xor(p, 2, 64);
      p += __shfl_xor(p, 4, 64);
      p += __shfl_xor(p, 8, 64);
      if (cr == 0) sP[wid][g * 4 + r] = p;
    }
  }
  __syncthreads();
  if (tid < MT) {
    float s = ba2[0];
#pragma unroll
    for (int w = 0; w < 8; ++w) s += sP[w][tid];
    L[m0 + tid] = s;
  }
}

// ---------------- Kernel B: fused softmax-pool + rho (R8 shape) ----------
// 512 threads, 16 visits/block (grid 1024 -> 8192 waves, ~8/SIMD).
// Each wave pools 2 visits: 16B/lane gather (4 lane-groups of 16 handle
// 4 codes/iter, 12 iters), group-reduce, stage bf16 hi/lo. Then rho's two
// MFMA layers at 1 n-tile per wave.
__global__ __launch_bounds__(512) void pool_rho(
    const int* __restrict__ ids, const float* __restrict__ L,
    const unsigned short* __restrict__ H2h,
    const unsigned short* __restrict__ frags,
    const float* __restrict__ br1, const float* __restrict__ br2,
    float* __restrict__ out) {
  __shared__ unsigned short Xh[2][MT][XLDP], Xl[2][MT][XLDP];
  const int tid = threadIdx.x, wid = tid >> 6, lane = tid & 63;
  const int cr = lane & 15, g = lane >> 4;   // g also = code-quarter q
  const int li = lane & 15;
  const int m0 = blockIdx.x * MT;

#pragma unroll
  for (int k = 0; k < 2; ++k) {
    const int vi = wid * 2 + k;          // row in this block's tile
    const int v = m0 + vi;
    int id = 0;
    float lg = -3.4e38f;
    if (lane < 48) {
      id = ids[(size_t)v * 48 + lane];
      if (id != 0) lg = L[id];  // PAD_IDX==0 masked
    }
    float mx = lg;
#pragma unroll
    for (int m = 32; m; m >>= 1) mx = fmaxf(mx, __shfl_xor(mx, m, 64));
    float e = (lg > -3.0e38f) ? __expf(lg - mx) : 0.f;
    float s = e;
#pragma unroll
    for (int m = 32; m; m >>= 1) s += __shfl_xor(s, m, 64);
    const float a = e / s;  // pads: exactly 0

    // 16B/lane gather: lane-group g handles codes 4*it+g; lane li reads
    // dims li*8..li*8+7 of the row. 12 iters cover 48 codes.
    float a8[8] = {0.f, 0.f, 0.f, 0.f, 0.f, 0.f, 0.f, 0.f};
#pragma unroll 4
    for (int c = 0; c < 12; ++c) {
      const int cc = 4 * c + g;
      const float ac = __shfl(a, cc, 64);
      const int idc = __shfl(id, cc, 64);
      const u16x8 hv = *(const u16x8*)(H2h + (size_t)idc * DIM + li * 8);
#pragma unroll
      for (int j = 0; j < 8; ++j)
        a8[j] = fmaf(ac, h2f(hv[j]), a8[j]);  // pad: ac==0 -> no-op
    }
#pragma unroll
    for (int j = 0; j < 8; ++j) {  // reduce across the 4 code-quarters
      a8[j] += __shfl_xor(a8[j], 16, 64);
      a8[j] += __shfl_xor(a8[j], 32, 64);
    }
    if (lane < 16) {  // stage pooled row as bf16 hi/lo for the MFMA layers
      u16x8 hh, hl;
#pragma unroll
      for (int j = 0; j < 8; ++j) {
        float hf;
        hh[j] = bf16_hi(a8[j], &hf);
        hl[j] = bf16_rd(a8[j] - hf);
      }
      *(u16x8*)&Xh[0][vi][li * 8] = hh;
      *(u16x8*)&Xl[0][vi][li * 8] = hl;
    }
  }
  __syncthreads();

  f32x4 acc2[1];
  // rho layer 1: silu(HP@Wr1+br1) -> Xh/Xl[1]   (frags slot 3)
  gemm_frag<1>(Xh[0], Xl[0], frags + 3 * 32768, frags + 3 * 32768 + 16384,
               wid, lane, acc2);
  {
    const int col = wid * 16 + cr;
    const float bv = br1[col];
#pragma unroll
    for (int r = 0; r < 4; ++r) {
      float o = silu_f(acc2[0][r] + bv);
      float hf;
      Xh[1][g * 4 + r][col] = bf16_hi(o, &hf);
      Xl[1][g * 4 + r][col] = bf16_rd(o - hf);
    }
  }
  __syncthreads();
  // rho layer 2: .@Wr2 + br2 -> out   (frags slot 4)
  gemm_frag<1>(Xh[1], Xl[1], frags + 4 * 32768, frags + 4 * 32768 + 16384,
               wid, lane, acc2);
  {
    const int col = wid * 16 + cr;
    const float bv = br2[col];
#pragma unroll
    for (int r = 0; r < 4; ++r)
      out[(size_t)(m0 + g * 4 + r) * DIM + col] = acc2[0][r] + bv;
  }
}

extern "C" void kernel_launch(void* const* d_in, const int* in_sizes, int n_in,
                              void* d_out, int out_size, void* d_ws,
                              size_t ws_size, hipStream_t stream) {
  const int*   ids = (const int*)  d_in[0];
  const float* emb = (const float*)d_in[1];
  const float* W1  = (const float*)d_in[2];
  const float* b1  = (const float*)d_in[3];
  const float* W2  = (const float*)d_in[4];
  const float* b2  = (const float*)d_in[5];
  const float* Wa1 = (const float*)d_in[6];
  const float* ba1 = (const float*)d_in[7];
  const float* wa2 = (const float*)d_in[8];
  const float* ba2 = (const float*)d_in[9];
  const float* Wr1 = (const float*)d_in[10];
  const float* br1 = (const float*)d_in[11];
  const float* Wr2 = (const float*)d_in[12];
  const float* br2 = (const float*)d_in[13];
  float* out = (float*)d_out;

  const int VOCAB = 20000, V = 16384;

  unsigned short* H2h = (unsigned short*)d_ws;        // 20000*128 fp16 (5.12MB)
  float* L = (float*)(H2h + (size_t)VOCAB * DIM);     // 20000 f32
  unsigned short* frags = (unsigned short*)(L + VOCAB);  // 5*2*16384 bf16

  prep_wfrags<<<40, 256, 0, stream>>>(W1, W2, Wa1, Wr1, Wr2, frags);
  vocab_mfma<<<VOCAB / MT, 512, 0, stream>>>(emb, frags, b1, b2, ba1, wa2,
                                             ba2, H2h, L);
  pool_rho<<<V / MT, 512, 0, stream>>>(ids, L, H2h, frags, br1, br2, out);
}

// Round 11
// 122.167 us; speedup vs baseline: 1.0461x; 1.0461x over previous
//
#include <hip/hip_runtime.h>
#include <math.h>

// LearnableVisitEncoder — R10 (resubmit; previous bench failed on container
// acquisition, no data). R9 regressed (reg-frag hoist broke 2-blocks/CU
// occupancy); R8 restored as base. R10 attacks the last untried ILP lever:
// pool's two visits per wave were SERIAL (softmax0 -> gather0 -> softmax1 ->
// gather1, unroll 4 = 4 outstanding loads). Now: both softmaxes first (2x
// ILP), one fused gather loop issuing both visits' loads per iter (unroll 6
// -> 12 loads in flight), launch_bounds(512,4) pins VGPR<=128 for 2
// blocks/CU. vocab_mfma / prep_wfrags: R8 verbatim.

#define DIM 128
#define MT 16
#define XLDP 136  // bf16 LDS row stride (272B = 17*16B): 16B-aligned rows

typedef float f32x4 __attribute__((ext_vector_type(4)));
typedef short short8 __attribute__((ext_vector_type(8)));
typedef unsigned short u16x8 __attribute__((ext_vector_type(8)));

#define MFMA(a, b, c) __builtin_amdgcn_mfma_f32_16x16x32_bf16(a, b, c, 0, 0, 0)

__device__ __forceinline__ float fast_rcp(float x) {
  return __builtin_amdgcn_rcpf(x);
}
__device__ __forceinline__ float silu_f(float v) {
  return v * fast_rcp(1.0f + __expf(-v));
}
__device__ __forceinline__ float tanh_f(float v) {
  float t = __expf(2.0f * v);       // inf-safe: v>>0 -> 1, v<<0 -> -1
  return 1.0f - 2.0f * fast_rcp(t + 1.0f);
}

// round-to-nearest bf16 split: x ~= hi + lo, |x-hi-lo| <= 2^-18 |x|
__device__ __forceinline__ unsigned short bf16_hi(float x, float* hif) {
  unsigned u = __builtin_bit_cast(unsigned, x);
  unsigned h = (u + 0x8000u) >> 16;
  *hif = __builtin_bit_cast(float, h << 16);
  return (unsigned short)h;
}
__device__ __forceinline__ unsigned short bf16_rd(float x) {
  unsigned u = __builtin_bit_cast(unsigned, x);
  return (unsigned short)((u + 0x8000u) >> 16);
}
// fp16 pack/unpack (v_cvt_f16_f32 / v_cvt_f32_f16)
__device__ __forceinline__ unsigned short f2h(float x) {
  return __builtin_bit_cast(unsigned short, (_Float16)x);
}
__device__ __forceinline__ float h2f(unsigned short u) {
  return (float)__builtin_bit_cast(_Float16, u);
}

// ---------------- W fragment prep ----------------
// frag element (t,s,lane,j) = W[k][n], k = s*32 + (lane>>4)*8 + j,
// n = t*16 + (lane&15); stored flat at ((t*4+s)*64+lane)*8+j.
__global__ __launch_bounds__(256) void prep_wfrags(
    const float* __restrict__ W1, const float* __restrict__ W2,
    const float* __restrict__ Wa1, const float* __restrict__ Wr1,
    const float* __restrict__ Wr2, unsigned short* __restrict__ frags) {
  const int m = blockIdx.x >> 3, chunk = blockIdx.x & 7;
  const float* W = (m == 0) ? W1 : (m == 1) ? W2 : (m == 2) ? Wa1
                  : (m == 3) ? Wr1 : Wr2;
  unsigned short* fh = frags + (size_t)m * 32768;
  unsigned short* fl = fh + 16384;
  const int fid = chunk * 256 + threadIdx.x;  // (t,s,lane) flat, < 2048
  const int lane = fid & 63, s = (fid >> 6) & 3, t = fid >> 8;
  const int k0 = s * 32 + (lane >> 4) * 8;
  const int n = t * 16 + (lane & 15);
#pragma unroll
  for (int j = 0; j < 8; ++j) {
    float w = W[(size_t)(k0 + j) * DIM + n];
    float hf;
    unsigned short h = bf16_hi(w, &hf);
    fh[fid * 8 + j] = h;
    fl[fid * 8 + j] = bf16_rd(w - hf);
  }
}

// stage MT x 128 fp32 rows -> hi/lo bf16 LDS tiles (256 threads)
__device__ __forceinline__ void stage_bf16(const float* __restrict__ src,
                                           unsigned short (*xh)[XLDP],
                                           unsigned short (*xl)[XLDP],
                                           int tid) {
  const float4* s = (const float4*)src;
#pragma unroll
  for (int tph = 0; tph < 2; ++tph) {
    int idx = tid + tph * 256;  // 512 float4 = 16 rows x 32
    int r = idx >> 5, c4 = idx & 31;
    float4 v = s[idx];
    float hf;
    ushort4 h, l;
    h.x = bf16_hi(v.x, &hf); l.x = bf16_rd(v.x - hf);
    h.y = bf16_hi(v.y, &hf); l.y = bf16_rd(v.y - hf);
    h.z = bf16_hi(v.z, &hf); l.z = bf16_rd(v.z - hf);
    h.w = bf16_hi(v.w, &hf); l.w = bf16_rd(v.w - hf);
    *(ushort4*)&xh[r][c4 * 4] = h;
    *(ushort4*)&xl[r][c4 * 4] = l;
  }
}

// one 16x128 @ 128x(16*NT) slice. 3 bf16 cross-products (hh, hl, lh) in two
// accumulators: fp32-level accuracy (ll <= 2^-18 rel), chain depth 8.
template <int NT>
__device__ __forceinline__ void gemm_frag(const unsigned short (*xh)[XLDP],
                                          const unsigned short (*xl)[XLDP],
                                          const unsigned short* __restrict__ bhp,
                                          const unsigned short* __restrict__ blp,
                                          int tt0, int lane, f32x4 acc[NT]) {
  const int cr = lane & 15, g = lane >> 4;
  short8 ah[4], al[4];
#pragma unroll
  for (int s = 0; s < 4; ++s) {  // A-frag: m=lane&15, k=s*32+(lane>>4)*8+j
    ah[s] = *(const short8*)&xh[cr][s * 32 + g * 8];
    al[s] = *(const short8*)&xl[cr][s * 32 + g * 8];
  }
#pragma unroll
  for (int t = 0; t < NT; ++t) {
    short8 bh[4], bl[4];
#pragma unroll
    for (int s = 0; s < 4; ++s) {
      bh[s] = *(const short8*)(bhp +
          ((size_t)((tt0 + t) * 4 + s) * 64 + lane) * 8);
      bl[s] = *(const short8*)(blp +
          ((size_t)((tt0 + t) * 4 + s) * 64 + lane) * 8);
    }
    f32x4 a0 = {0.f, 0.f, 0.f, 0.f}, a1 = {0.f, 0.f, 0.f, 0.f};
#pragma unroll
    for (int s = 0; s < 4; ++s) {
      a0 = MFMA(ah[s], bh[s], a0);
      a1 = MFMA(ah[s], bl[s], a1);
      a1 = MFMA(al[s], bh[s], a1);
    }
    acc[t] = a0 + a1;
  }
}

// ---------------- Kernel A: vocab side (R8 shape) ----------------
// 256 threads = 4 waves; wave wid owns n-tiles wid*2, wid*2+1.
// Grid 1250 blocks -> 5000 waves (~4.9/SIMD).
__global__ __launch_bounds__(256) void vocab_mfma(
    const float* __restrict__ emb, const unsigned short* __restrict__ frags,
    const float* __restrict__ b1, const float* __restrict__ b2,
    const float* __restrict__ ba1, const float* __restrict__ wa2,
    const float* __restrict__ ba2, unsigned short* __restrict__ H2h,
    float* __restrict__ L) {
  __shared__ unsigned short Xh[2][MT][XLDP], Xl[2][MT][XLDP];
  __shared__ float sP[4][MT];
  const int tid = threadIdx.x, wid = tid >> 6, lane = tid & 63;
  const int cr = lane & 15, g = lane >> 4;
  const int m0 = blockIdx.x * MT;

  stage_bf16(emb + (size_t)m0 * DIM, Xh[0], Xl[0], tid);
  __syncthreads();

  f32x4 acc[2];
  // layer 1: silu(emb@W1+b1) -> Xh/Xl[1]
  gemm_frag<2>(Xh[0], Xl[0], frags, frags + 16384, wid * 2, lane, acc);
#pragma unroll
  for (int t = 0; t < 2; ++t) {
    const int col = (wid * 2 + t) * 16 + cr;
    const float bv = b1[col];
#pragma unroll
    for (int r = 0; r < 4; ++r) {
      float o = silu_f(acc[t][r] + bv);
      float hf;
      Xh[1][g * 4 + r][col] = bf16_hi(o, &hf);
      Xl[1][g * 4 + r][col] = bf16_rd(o - hf);
    }
  }
  __syncthreads();
  // layer 2: silu(.@W2+b2) -> Xh/Xl[0] + global H2h (fp16)
  gemm_frag<2>(Xh[1], Xl[1], frags + 32768, frags + 32768 + 16384,
               wid * 2, lane, acc);
#pragma unroll
  for (int t = 0; t < 2; ++t) {
    const int col = (wid * 2 + t) * 16 + cr;
    const float bv = b2[col];
#pragma unroll
    for (int r = 0; r < 4; ++r) {
      float o = silu_f(acc[t][r] + bv);
      float hf;
      const int row = g * 4 + r;
      Xh[0][row][col] = bf16_hi(o, &hf);
      Xl[0][row][col] = bf16_rd(o - hf);
      H2h[(size_t)(m0 + row) * DIM + col] = f2h(o);
    }
  }
  __syncthreads();
  // layer 3: tanh(.@Wa1+ba1) . wa2 -> L
  gemm_frag<2>(Xh[0], Xl[0], frags + 65536, frags + 65536 + 16384,
               wid * 2, lane, acc);
  {
    float pl[4] = {0.f, 0.f, 0.f, 0.f};
#pragma unroll
    for (int t = 0; t < 2; ++t) {
      const int col = (wid * 2 + t) * 16 + cr;
      const float bav = ba1[col], wav = wa2[col];
#pragma unroll
      for (int r = 0; r < 4; ++r)
        pl[r] = fmaf(tanh_f(acc[t][r] + bav), wav, pl[r]);
    }
#pragma unroll
    for (int r = 0; r < 4; ++r) {
      float p = pl[r];
      p += __shfl_xor(p, 1, 64);  // reduce over the 16 cols (lane&15)
      p += __shfl_xor(p, 2, 64);
      p += __shfl_xor(p, 4, 64);
      p += __shfl_xor(p, 8, 64);
      if (cr == 0) sP[wid][g * 4 + r] = p;
    }
  }
  __syncthreads();
  if (tid < MT)
    L[m0 + tid] = sP[0][tid] + sP[1][tid] + sP[2][tid] + sP[3][tid] + ba2[0];
}

// ---------------- Kernel B: fused softmax-pool + rho ----------------
// 512 threads, 16 visits/block (grid 1024). Each wave pools its TWO visits
// with interleaved gathers: both softmaxes first (independent shuffle
// chains), then one fused loop issuing both visits' 16B loads per iter
// (unroll 6 -> 12 loads in flight). Then rho's two MFMA layers, 1
// n-tile/wave. launch_bounds(512,4): VGPR<=128 -> 2 blocks/CU.
__global__ __launch_bounds__(512, 4) void pool_rho(
    const int* __restrict__ ids, const float* __restrict__ L,
    const unsigned short* __restrict__ H2h,
    const unsigned short* __restrict__ frags,
    const float* __restrict__ br1, const float* __restrict__ br2,
    float* __restrict__ out) {
  __shared__ unsigned short Xh[2][MT][XLDP], Xl[2][MT][XLDP];
  const int tid = threadIdx.x, wid = tid >> 6, lane = tid & 63;
  const int cr = lane & 15, g = lane >> 4;   // g also = code-quarter q
  const int li = lane & 15;
  const int m0 = blockIdx.x * MT;

  const int vi0 = wid * 2, vi1 = vi0 + 1;
  const int v0 = m0 + vi0, v1 = m0 + vi1;

  // --- both softmaxes first (independent chains, 2x shuffle ILP) ---
  int id0 = 0, id1 = 0;
  float lg0 = -3.4e38f, lg1 = -3.4e38f;
  if (lane < 48) {
    id0 = ids[(size_t)v0 * 48 + lane];
    id1 = ids[(size_t)v1 * 48 + lane];
    if (id0 != 0) lg0 = L[id0];  // PAD_IDX==0 masked
    if (id1 != 0) lg1 = L[id1];
  }
  float mx0 = lg0, mx1 = lg1;
#pragma unroll
  for (int m = 32; m; m >>= 1) {
    mx0 = fmaxf(mx0, __shfl_xor(mx0, m, 64));
    mx1 = fmaxf(mx1, __shfl_xor(mx1, m, 64));
  }
  float e0 = (lg0 > -3.0e38f) ? __expf(lg0 - mx0) : 0.f;
  float e1 = (lg1 > -3.0e38f) ? __expf(lg1 - mx1) : 0.f;
  float s0 = e0, s1 = e1;
#pragma unroll
  for (int m = 32; m; m >>= 1) {
    s0 += __shfl_xor(s0, m, 64);
    s1 += __shfl_xor(s1, m, 64);
  }
  const float a0 = e0 / s0, a1 = e1 / s1;  // pads: exactly 0

  // --- fused gather: lane-group g handles codes 4*it+g for BOTH visits ---
  float p0[8] = {0.f, 0.f, 0.f, 0.f, 0.f, 0.f, 0.f, 0.f};
  float p1[8] = {0.f, 0.f, 0.f, 0.f, 0.f, 0.f, 0.f, 0.f};
#pragma unroll 6
  for (int c = 0; c < 12; ++c) {
    const int cc = 4 * c + g;
    const float ac0 = __shfl(a0, cc, 64);
    const int ic0 = __shfl(id0, cc, 64);
    const float ac1 = __shfl(a1, cc, 64);
    const int ic1 = __shfl(id1, cc, 64);
    const u16x8 h0 = *(const u16x8*)(H2h + (size_t)ic0 * DIM + li * 8);
    const u16x8 h1 = *(const u16x8*)(H2h + (size_t)ic1 * DIM + li * 8);
#pragma unroll
    for (int j = 0; j < 8; ++j) {
      p0[j] = fmaf(ac0, h2f(h0[j]), p0[j]);  // pad: ac==0 -> no-op
      p1[j] = fmaf(ac1, h2f(h1[j]), p1[j]);
    }
  }
#pragma unroll
  for (int j = 0; j < 8; ++j) {  // reduce across the 4 code-quarters
    p0[j] += __shfl_xor(p0[j], 16, 64);
    p0[j] += __shfl_xor(p0[j], 32, 64);
    p1[j] += __shfl_xor(p1[j], 16, 64);
    p1[j] += __shfl_xor(p1[j], 32, 64);
  }
  if (lane < 16) {  // stage both pooled rows as bf16 hi/lo
    u16x8 hh0, hl0, hh1, hl1;
#pragma unroll
    for (int j = 0; j < 8; ++j) {
      float hf;
      hh0[j] = bf16_hi(p0[j], &hf);
      hl0[j] = bf16_rd(p0[j] - hf);
      hh1[j] = bf16_hi(p1[j], &hf);
      hl1[j] = bf16_rd(p1[j] - hf);
    }
    *(u16x8*)&Xh[0][vi0][li * 8] = hh0;
    *(u16x8*)&Xl[0][vi0][li * 8] = hl0;
    *(u16x8*)&Xh[0][vi1][li * 8] = hh1;
    *(u16x8*)&Xl[0][vi1][li * 8] = hl1;
  }
  __syncthreads();

  f32x4 acc2[1];
  // rho layer 1: silu(HP@Wr1+br1) -> Xh/Xl[1]   (frags slot 3)
  gemm_frag<1>(Xh[0], Xl[0], frags + 3 * 32768, frags + 3 * 32768 + 16384,
               wid, lane, acc2);
  {
    const int col = wid * 16 + cr;
    const float bv = br1[col];
#pragma unroll
    for (int r = 0; r < 4; ++r) {
      float o = silu_f(acc2[0][r] + bv);
      float hf;
      Xh[1][g * 4 + r][col] = bf16_hi(o, &hf);
      Xl[1][g * 4 + r][col] = bf16_rd(o - hf);
    }
  }
  __syncthreads();
  // rho layer 2: .@Wr2 + br2 -> out   (frags slot 4)
  gemm_frag<1>(Xh[1], Xl[1], frags + 4 * 32768, frags + 4 * 32768 + 16384,
               wid, lane, acc2);
  {
    const int col = wid * 16 + cr;
    const float bv = br2[col];
#pragma unroll
    for (int r = 0; r < 4; ++r)
      out[(size_t)(m0 + g * 4 + r) * DIM + col] = acc2[0][r] + bv;
  }
}

extern "C" void kernel_launch(void* const* d_in, const int* in_sizes, int n_in,
                              void* d_out, int out_size, void* d_ws,
                              size_t ws_size, hipStream_t stream) {
  const int*   ids = (const int*)  d_in[0];
  const float* emb = (const float*)d_in[1];
  const float* W1  = (const float*)d_in[2];
  const float* b1  = (const float*)d_in[3];
  const float* W2  = (const float*)d_in[4];
  const float* b2  = (const float*)d_in[5];
  const float* Wa1 = (const float*)d_in[6];
  const float* ba1 = (const float*)d_in[7];
  const float* wa2 = (const float*)d_in[8];
  const float* ba2 = (const float*)d_in[9];
  const float* Wr1 = (const float*)d_in[10];
  const float* br1 = (const float*)d_in[11];
  const float* Wr2 = (const float*)d_in[12];
  const float* br2 = (const float*)d_in[13];
  float* out = (float*)d_out;

  const int VOCAB = 20000, V = 16384;

  unsigned short* H2h = (unsigned short*)d_ws;        // 20000*128 fp16 (5.12MB)
  float* L = (float*)(H2h + (size_t)VOCAB * DIM);     // 20000 f32
  unsigned short* frags = (unsigned short*)(L + VOCAB);  // 5*2*16384 bf16

  prep_wfrags<<<40, 256, 0, stream>>>(W1, W2, Wa1, Wr1, Wr2, frags);
  vocab_mfma<<<VOCAB / MT, 256, 0, stream>>>(emb, frags, b1, b2, ba1, wa2,
                                             ba2, H2h, L);
  pool_rho<<<V / MT, 512, 0, stream>>>(ids, L, H2h, frags, br1, br2, out);
}

// Round 12
// 121.616 us; speedup vs baseline: 1.0508x; 1.0045x over previous
//
#include <hip/hip_runtime.h>
#include <math.h>

// LearnableVisitEncoder — R12.
// R10 (dual-visit pool interleave) = best at 122.2us; pool at its L3 gather
// floor (H2h 5.12MB > one XCD's 4MB L2). R12 probes the one untested vocab
// geometry: MT=32 rows, 8 waves, 1 n-tile x 2 row-strips per wave. Same
// 5000-wave TLP as the winning R5 shape (625 blocks x 8 waves), but frag
// traffic halves (240->120MB) and B-load:MFMA ratio improves 16:24 -> 8:24.
// Strips processed serially (B-frags shared, A-frags+epilogue per strip) to
// stay under 128 VGPR: launch_bounds(512,4) -> 2 blocks/CU.
// pool_rho / prep_wfrags: R10 verbatim.

#define DIM 128
#define MT 16    // pool_rho tile rows (unchanged)
#define MT2 32   // vocab tile rows
#define XLDP 136 // bf16 LDS row stride (272B = 17*16B): 16B-aligned rows

typedef float f32x4 __attribute__((ext_vector_type(4)));
typedef short short8 __attribute__((ext_vector_type(8)));
typedef unsigned short u16x8 __attribute__((ext_vector_type(8)));

#define MFMA(a, b, c) __builtin_amdgcn_mfma_f32_16x16x32_bf16(a, b, c, 0, 0, 0)

__device__ __forceinline__ float fast_rcp(float x) {
  return __builtin_amdgcn_rcpf(x);
}
__device__ __forceinline__ float silu_f(float v) {
  return v * fast_rcp(1.0f + __expf(-v));
}
__device__ __forceinline__ float tanh_f(float v) {
  float t = __expf(2.0f * v);       // inf-safe: v>>0 -> 1, v<<0 -> -1
  return 1.0f - 2.0f * fast_rcp(t + 1.0f);
}

// round-to-nearest bf16 split: x ~= hi + lo, |x-hi-lo| <= 2^-18 |x|
__device__ __forceinline__ unsigned short bf16_hi(float x, float* hif) {
  unsigned u = __builtin_bit_cast(unsigned, x);
  unsigned h = (u + 0x8000u) >> 16;
  *hif = __builtin_bit_cast(float, h << 16);
  return (unsigned short)h;
}
__device__ __forceinline__ unsigned short bf16_rd(float x) {
  unsigned u = __builtin_bit_cast(unsigned, x);
  return (unsigned short)((u + 0x8000u) >> 16);
}
// fp16 pack/unpack (v_cvt_f16_f32 / v_cvt_f32_f16)
__device__ __forceinline__ unsigned short f2h(float x) {
  return __builtin_bit_cast(unsigned short, (_Float16)x);
}
__device__ __forceinline__ float h2f(unsigned short u) {
  return (float)__builtin_bit_cast(_Float16, u);
}

// ---------------- W fragment prep ----------------
// frag element (t,s,lane,j) = W[k][n], k = s*32 + (lane>>4)*8 + j,
// n = t*16 + (lane&15); stored flat at ((t*4+s)*64+lane)*8+j.
__global__ __launch_bounds__(256) void prep_wfrags(
    const float* __restrict__ W1, const float* __restrict__ W2,
    const float* __restrict__ Wa1, const float* __restrict__ Wr1,
    const float* __restrict__ Wr2, unsigned short* __restrict__ frags) {
  const int m = blockIdx.x >> 3, chunk = blockIdx.x & 7;
  const float* W = (m == 0) ? W1 : (m == 1) ? W2 : (m == 2) ? Wa1
                  : (m == 3) ? Wr1 : Wr2;
  unsigned short* fh = frags + (size_t)m * 32768;
  unsigned short* fl = fh + 16384;
  const int fid = chunk * 256 + threadIdx.x;  // (t,s,lane) flat, < 2048
  const int lane = fid & 63, s = (fid >> 6) & 3, t = fid >> 8;
  const int k0 = s * 32 + (lane >> 4) * 8;
  const int n = t * 16 + (lane & 15);
#pragma unroll
  for (int j = 0; j < 8; ++j) {
    float w = W[(size_t)(k0 + j) * DIM + n];
    float hf;
    unsigned short h = bf16_hi(w, &hf);
    fh[fid * 8 + j] = h;
    fl[fid * 8 + j] = bf16_rd(w - hf);
  }
}

// load one n-tile's B-frags (8 short8s = 32 VGPR)
__device__ __forceinline__ void loadB(const unsigned short* __restrict__ bhp,
                                      const unsigned short* __restrict__ blp,
                                      int tt, int lane, short8 bh[4],
                                      short8 bl[4]) {
#pragma unroll
  for (int s = 0; s < 4; ++s) {
    bh[s] = *(const short8*)(bhp + ((size_t)(tt * 4 + s) * 64 + lane) * 8);
    bl[s] = *(const short8*)(blp + ((size_t)(tt * 4 + s) * 64 + lane) * 8);
  }
}

// one 16-row strip x n-tile: A from LDS, B in registers. 3 cross-products
// (hh, hl, lh) in two accumulators: fp32-level accuracy, chain depth 8.
__device__ __forceinline__ f32x4 gemm_strip(const unsigned short (*xh)[XLDP],
                                            const unsigned short (*xl)[XLDP],
                                            int st, const short8 bh[4],
                                            const short8 bl[4], int lane) {
  const int cr = lane & 15, g = lane >> 4;
  f32x4 a0 = {0.f, 0.f, 0.f, 0.f}, a1 = {0.f, 0.f, 0.f, 0.f};
#pragma unroll
  for (int s = 0; s < 4; ++s) {
    short8 ah = *(const short8*)&xh[st * 16 + cr][s * 32 + g * 8];
    short8 al = *(const short8*)&xl[st * 16 + cr][s * 32 + g * 8];
    a0 = MFMA(ah, bh[s], a0);
    a1 = MFMA(ah, bl[s], a1);
    a1 = MFMA(al, bh[s], a1);
  }
  return a0 + a1;
}

// ---------------- Kernel A: vocab side (MT2=32, 8 waves) ----------------
// 512 threads = 8 waves, grid 625 (5000 waves). Wave wid owns n-tile wid
// (cols wid*16..+15) across both 16-row strips, processed serially.
__global__ __launch_bounds__(512, 4) void vocab_mfma(
    const float* __restrict__ emb, const unsigned short* __restrict__ frags,
    const float* __restrict__ b1, const float* __restrict__ b2,
    const float* __restrict__ ba1, const float* __restrict__ wa2,
    const float* __restrict__ ba2, unsigned short* __restrict__ H2h,
    float* __restrict__ L) {
  __shared__ unsigned short Xh[2][MT2][XLDP], Xl[2][MT2][XLDP];
  __shared__ float sP[8][MT2];
  const int tid = threadIdx.x, wid = tid >> 6, lane = tid & 63;
  const int cr = lane & 15, g = lane >> 4;
  const int m0 = blockIdx.x * MT2;
  const int col = wid * 16 + cr;

  // stage 32x128 fp32 -> hi/lo bf16 (1024 float4, 2 per thread)
  {
    const float4* s = (const float4*)(emb + (size_t)m0 * DIM);
#pragma unroll
    for (int tph = 0; tph < 2; ++tph) {
      int idx = tid + tph * 512;
      int r = idx >> 5, c4 = idx & 31;
      float4 v = s[idx];
      float hf;
      ushort4 h, l;
      h.x = bf16_hi(v.x, &hf); l.x = bf16_rd(v.x - hf);
      h.y = bf16_hi(v.y, &hf); l.y = bf16_rd(v.y - hf);
      h.z = bf16_hi(v.z, &hf); l.z = bf16_rd(v.z - hf);
      h.w = bf16_hi(v.w, &hf); l.w = bf16_rd(v.w - hf);
      *(ushort4*)&Xh[0][r][c4 * 4] = h;
      *(ushort4*)&Xl[0][r][c4 * 4] = l;
    }
  }
  __syncthreads();

  short8 bh[4], bl[4];
  // layer 1: silu(emb@W1+b1) -> Xh/Xl[1]
  loadB(frags, frags + 16384, wid, lane, bh, bl);
  {
    const float bv = b1[col];
#pragma unroll
    for (int st = 0; st < 2; ++st) {
      f32x4 acc = gemm_strip(Xh[0], Xl[0], st, bh, bl, lane);
#pragma unroll
      for (int r = 0; r < 4; ++r) {
        float o = silu_f(acc[r] + bv);
        float hf;
        Xh[1][st * 16 + g * 4 + r][col] = bf16_hi(o, &hf);
        Xl[1][st * 16 + g * 4 + r][col] = bf16_rd(o - hf);
      }
    }
  }
  __syncthreads();
  // layer 2: silu(.@W2+b2) -> Xh/Xl[0] + global H2h (fp16)
  loadB(frags + 32768, frags + 32768 + 16384, wid, lane, bh, bl);
  {
    const float bv = b2[col];
#pragma unroll
    for (int st = 0; st < 2; ++st) {
      f32x4 acc = gemm_strip(Xh[1], Xl[1], st, bh, bl, lane);
#pragma unroll
      for (int r = 0; r < 4; ++r) {
        float o = silu_f(acc[r] + bv);
        float hf;
        const int row = st * 16 + g * 4 + r;
        Xh[0][row][col] = bf16_hi(o, &hf);
        Xl[0][row][col] = bf16_rd(o - hf);
        H2h[(size_t)(m0 + row) * DIM + col] = f2h(o);
      }
    }
  }
  __syncthreads();
  // layer 3: tanh(.@Wa1+ba1) . wa2 -> sP -> L
  loadB(frags + 65536, frags + 65536 + 16384, wid, lane, bh, bl);
  {
    const float bav = ba1[col], wav = wa2[col];
#pragma unroll
    for (int st = 0; st < 2; ++st) {
      f32x4 acc = gemm_strip(Xh[0], Xl[0], st, bh, bl, lane);
#pragma unroll
      for (int r = 0; r < 4; ++r) {
        float p = tanh_f(acc[r] + bav) * wav;
        p += __shfl_xor(p, 1, 64);  // reduce over the 16 cols (lane&15)
        p += __shfl_xor(p, 2, 64);
        p += __shfl_xor(p, 4, 64);
        p += __shfl_xor(p, 8, 64);
        if (cr == 0) sP[wid][st * 16 + g * 4 + r] = p;
      }
    }
  }
  __syncthreads();
  if (tid < MT2) {
    float s = ba2[0];
#pragma unroll
    for (int w = 0; w < 8; ++w) s += sP[w][tid];
    L[m0 + tid] = s;
  }
}

// one 16x128 @ 128x16 slice from L2 frag arrays (pool_rho path)
template <int NT>
__device__ __forceinline__ void gemm_frag(const unsigned short (*xh)[XLDP],
                                          const unsigned short (*xl)[XLDP],
                                          const unsigned short* __restrict__ bhp,
                                          const unsigned short* __restrict__ blp,
                                          int tt0, int lane, f32x4 acc[NT]) {
  const int cr = lane & 15, g = lane >> 4;
  short8 ah[4], al[4];
#pragma unroll
  for (int s = 0; s < 4; ++s) {  // A-frag: m=lane&15, k=s*32+(lane>>4)*8+j
    ah[s] = *(const short8*)&xh[cr][s * 32 + g * 8];
    al[s] = *(const short8*)&xl[cr][s * 32 + g * 8];
  }
#pragma unroll
  for (int t = 0; t < NT; ++t) {
    short8 bh[4], bl[4];
#pragma unroll
    for (int s = 0; s < 4; ++s) {
      bh[s] = *(const short8*)(bhp +
          ((size_t)((tt0 + t) * 4 + s) * 64 + lane) * 8);
      bl[s] = *(const short8*)(blp +
          ((size_t)((tt0 + t) * 4 + s) * 64 + lane) * 8);
    }
    f32x4 a0 = {0.f, 0.f, 0.f, 0.f}, a1 = {0.f, 0.f, 0.f, 0.f};
#pragma unroll
    for (int s = 0; s < 4; ++s) {
      a0 = MFMA(ah[s], bh[s], a0);
      a1 = MFMA(ah[s], bl[s], a1);
      a1 = MFMA(al[s], bh[s], a1);
    }
    acc[t] = a0 + a1;
  }
}

// ---------------- Kernel B: fused softmax-pool + rho (R10 shape) ----------
// 512 threads, 16 visits/block (grid 1024). Each wave pools its TWO visits
// with interleaved gathers: both softmaxes first, then one fused loop
// issuing both visits' 16B loads per iter (unroll 6 -> 12 loads in flight).
// Then rho's two MFMA layers, 1 n-tile/wave. launch_bounds(512,4).
__global__ __launch_bounds__(512, 4) void pool_rho(
    const int* __restrict__ ids, const float* __restrict__ L,
    const unsigned short* __restrict__ H2h,
    const unsigned short* __restrict__ frags,
    const float* __restrict__ br1, const float* __restrict__ br2,
    float* __restrict__ out) {
  __shared__ unsigned short Xh[2][MT][XLDP], Xl[2][MT][XLDP];
  const int tid = threadIdx.x, wid = tid >> 6, lane = tid & 63;
  const int cr = lane & 15, g = lane >> 4;   // g also = code-quarter q
  const int li = lane & 15;
  const int m0 = blockIdx.x * MT;

  const int vi0 = wid * 2, vi1 = vi0 + 1;
  const int v0 = m0 + vi0, v1 = m0 + vi1;

  // --- both softmaxes first (independent chains, 2x shuffle ILP) ---
  int id0 = 0, id1 = 0;
  float lg0 = -3.4e38f, lg1 = -3.4e38f;
  if (lane < 48) {
    id0 = ids[(size_t)v0 * 48 + lane];
    id1 = ids[(size_t)v1 * 48 + lane];
    if (id0 != 0) lg0 = L[id0];  // PAD_IDX==0 masked
    if (id1 != 0) lg1 = L[id1];
  }
  float mx0 = lg0, mx1 = lg1;
#pragma unroll
  for (int m = 32; m; m >>= 1) {
    mx0 = fmaxf(mx0, __shfl_xor(mx0, m, 64));
    mx1 = fmaxf(mx1, __shfl_xor(mx1, m, 64));
  }
  float e0 = (lg0 > -3.0e38f) ? __expf(lg0 - mx0) : 0.f;
  float e1 = (lg1 > -3.0e38f) ? __expf(lg1 - mx1) : 0.f;
  float s0 = e0, s1 = e1;
#pragma unroll
  for (int m = 32; m; m >>= 1) {
    s0 += __shfl_xor(s0, m, 64);
    s1 += __shfl_xor(s1, m, 64);
  }
  const float a0 = e0 / s0, a1 = e1 / s1;  // pads: exactly 0

  // --- fused gather: lane-group g handles codes 4*it+g for BOTH visits ---
  float p0[8] = {0.f, 0.f, 0.f, 0.f, 0.f, 0.f, 0.f, 0.f};
  float p1[8] = {0.f, 0.f, 0.f, 0.f, 0.f, 0.f, 0.f, 0.f};
#pragma unroll 6
  for (int c = 0; c < 12; ++c) {
    const int cc = 4 * c + g;
    const float ac0 = __shfl(a0, cc, 64);
    const int ic0 = __shfl(id0, cc, 64);
    const float ac1 = __shfl(a1, cc, 64);
    const int ic1 = __shfl(id1, cc, 64);
    const u16x8 h0 = *(const u16x8*)(H2h + (size_t)ic0 * DIM + li * 8);
    const u16x8 h1 = *(const u16x8*)(H2h + (size_t)ic1 * DIM + li * 8);
#pragma unroll
    for (int j = 0; j < 8; ++j) {
      p0[j] = fmaf(ac0, h2f(h0[j]), p0[j]);  // pad: ac==0 -> no-op
      p1[j] = fmaf(ac1, h2f(h1[j]), p1[j]);
    }
  }
#pragma unroll
  for (int j = 0; j < 8; ++j) {  // reduce across the 4 code-quarters
    p0[j] += __shfl_xor(p0[j], 16, 64);
    p0[j] += __shfl_xor(p0[j], 32, 64);
    p1[j] += __shfl_xor(p1[j], 16, 64);
    p1[j] += __shfl_xor(p1[j], 32, 64);
  }
  if (lane < 16) {  // stage both pooled rows as bf16 hi/lo
    u16x8 hh0, hl0, hh1, hl1;
#pragma unroll
    for (int j = 0; j < 8; ++j) {
      float hf;
      hh0[j] = bf16_hi(p0[j], &hf);
      hl0[j] = bf16_rd(p0[j] - hf);
      hh1[j] = bf16_hi(p1[j], &hf);
      hl1[j] = bf16_rd(p1[j] - hf);
    }
    *(u16x8*)&Xh[0][vi0][li * 8] = hh0;
    *(u16x8*)&Xl[0][vi0][li * 8] = hl0;
    *(u16x8*)&Xh[0][vi1][li * 8] = hh1;
    *(u16x8*)&Xl[0][vi1][li * 8] = hl1;
  }
  __syncthreads();

  f32x4 acc2[1];
  // rho layer 1: silu(HP@Wr1+br1) -> Xh/Xl[1]   (frags slot 3)
  gemm_frag<1>(Xh[0], Xl[0], frags + 3 * 32768, frags + 3 * 32768 + 16384,
               wid, lane, acc2);
  {
    const int col = wid * 16 + cr;
    const float bv = br1[col];
#pragma unroll
    for (int r = 0; r < 4; ++r) {
      float o = silu_f(acc2[0][r] + bv);
      float hf;
      Xh[1][g * 4 + r][col] = bf16_hi(o, &hf);
      Xl[1][g * 4 + r][col] = bf16_rd(o - hf);
    }
  }
  __syncthreads();
  // rho layer 2: .@Wr2 + br2 -> out   (frags slot 4)
  gemm_frag<1>(Xh[1], Xl[1], frags + 4 * 32768, frags + 4 * 32768 + 16384,
               wid, lane, acc2);
  {
    const int col = wid * 16 + cr;
    const float bv = br2[col];
#pragma unroll
    for (int r = 0; r < 4; ++r)
      out[(size_t)(m0 + g * 4 + r) * DIM + col] = acc2[0][r] + bv;
  }
}

extern "C" void kernel_launch(void* const* d_in, const int* in_sizes, int n_in,
                              void* d_out, int out_size, void* d_ws,
                              size_t ws_size, hipStream_t stream) {
  const int*   ids = (const int*)  d_in[0];
  const float* emb = (const float*)d_in[1];
  const float* W1  = (const float*)d_in[2];
  const float* b1  = (const float*)d_in[3];
  const float* W2  = (const float*)d_in[4];
  const float* b2  = (const float*)d_in[5];
  const float* Wa1 = (const float*)d_in[6];
  const float* ba1 = (const float*)d_in[7];
  const float* wa2 = (const float*)d_in[8];
  const float* ba2 = (const float*)d_in[9];
  const float* Wr1 = (const float*)d_in[10];
  const float* br1 = (const float*)d_in[11];
  const float* Wr2 = (const float*)d_in[12];
  const float* br2 = (const float*)d_in[13];
  float* out = (float*)d_out;

  const int VOCAB = 20000, V = 16384;

  unsigned short* H2h = (unsigned short*)d_ws;        // 20000*128 fp16 (5.12MB)
  float* L = (float*)(H2h + (size_t)VOCAB * DIM);     // 20000 f32
  unsigned short* frags = (unsigned short*)(L + VOCAB);  // 5*2*16384 bf16

  prep_wfrags<<<40, 256, 0, stream>>>(W1, W2, Wa1, Wr1, Wr2, frags);
  vocab_mfma<<<VOCAB / MT2, 512, 0, stream>>>(emb, frags, b1, b2, ba1, wa2,
                                              ba2, H2h, L);
  pool_rho<<<V / MT, 512, 0, stream>>>(ids, L, H2h, frags, br1, br2, out);
}